// Round 9
// baseline (241.424 us; speedup 1.0000x reference)
//
#include <hip/hip_runtime.h>
#include <hip/hip_fp16.h>

#define NTOT 8192
#define NHALF 4096
#define DIM 256
#define LOG2E 1.4426950408889634f
#define NEG_BIG -1e30f
#define COLSPLIT 8
#define BM 128
#define BN 64
#define CPB (NTOT / COLSPLIT) /* 1024 cols per block */
#define NBLK ((NTOT / BM) * COLSPLIT) /* 512 blocks */

typedef _Float16 half8 __attribute__((ext_vector_type(8)));
typedef float floatx4 __attribute__((ext_vector_type(4)));

// ---- fused normalize + target-sim: wave handles row r (z1) and r+N (z2) ----
// grid = 1024 x 256 (4 waves = 4 row-pairs per block). Also re-arms cnt.
__global__ __launch_bounds__(256) void k_norm_tsim(const float* __restrict__ z1,
                                                   const float* __restrict__ z2,
                                                   __half* __restrict__ zn,
                                                   float* __restrict__ tsim,
                                                   unsigned int* __restrict__ cnt) {
  if (blockIdx.x == 0 && threadIdx.x == 0) *cnt = 0;
  int row = blockIdx.x * 4 + (threadIdx.x >> 6);  // 0..4095
  int lane = threadIdx.x & 63;
  float4 va = ((const float4*)(z1 + (size_t)row * DIM))[lane];
  float4 vb = ((const float4*)(z2 + (size_t)row * DIM))[lane];
  float ssa = va.x * va.x + va.y * va.y + va.z * va.z + va.w * va.w;
  float ssb = vb.x * vb.x + vb.y * vb.y + vb.z * vb.z + vb.w * vb.w;
  float sab = va.x * vb.x + va.y * vb.y + va.z * vb.z + va.w * vb.w;
#pragma unroll
  for (int m = 1; m < 64; m <<= 1) {
    ssa += __shfl_xor(ssa, m);
    ssb += __shfl_xor(ssb, m);
    sab += __shfl_xor(sab, m);
  }
  float inva = 1.0f / fmaxf(sqrtf(ssa), 1e-8f);
  float invb = 1.0f / fmaxf(sqrtf(ssb), 1e-8f);
  __half2 a0, a1, b0, b1;
  a0.x = __float2half_rn(va.x * inva);
  a0.y = __float2half_rn(va.y * inva);
  a1.x = __float2half_rn(va.z * inva);
  a1.y = __float2half_rn(va.w * inva);
  b0.x = __float2half_rn(vb.x * invb);
  b0.y = __float2half_rn(vb.y * invb);
  b1.x = __float2half_rn(vb.z * invb);
  b1.y = __float2half_rn(vb.w * invb);
  __half2* da = (__half2*)(zn + (size_t)row * DIM + lane * 4);
  __half2* db = (__half2*)(zn + (size_t)(row + NHALF) * DIM + lane * 4);
  da[0] = a0;
  da[1] = a1;
  db[0] = b0;
  db[1] = b1;
  if (lane == 0) {
    float t = sab * inva * invb;  // zn_r . zn_{r+N}, fp32-exact
    tsim[row] = t;
    tsim[row + NHALF] = t;
  }
}

// ---------------- main fused S-pass (R0's proven 70.6us hot loop, verbatim)
// + deadlock-free last-block final reduce ----------------
// grid = 64 rowTiles x 8 colSplits = 512 blocks, 256 threads (4 waves x 32 rows)
__global__ __launch_bounds__(256, 2) void k_main(const __half* __restrict__ zn,
                                                 const float* __restrict__ logT,
                                                 float* __restrict__ pM,
                                                 float* __restrict__ pL,
                                                 int* __restrict__ pI,
                                                 const float* __restrict__ tsim,
                                                 unsigned int* __restrict__ cnt,
                                                 float* __restrict__ out) {
  __shared__ uint4 lds[BN * 32];  // 64 rows x 32 x 16B = 32 KB, xor-swizzled
  __shared__ int lastFlag;

  int bx = blockIdx.x;
  int rowTile = bx >> 3;
  int colq = bx & 7;
  int rowBase = rowTile * BM;
  int colBase = colq * CPB;
  int tid = threadIdx.x;
  int w = tid >> 6;
  int lane = tid & 63;
  int quad = lane >> 4;
  int cl = lane & 15;

  float invT = expf(-logT[0]);
  float kk = invT * LOG2E;

  // A fragments in registers: wave owns rows [rowBase+w*32, +32), 2 tiles of 16
  half8 a[2][8];
  {
    int ar0 = rowBase + w * 32 + cl;
    int ar1 = ar0 + 16;
#pragma unroll
    for (int ks = 0; ks < 8; ks++) {
      a[0][ks] = *(const half8*)(zn + (size_t)ar0 * DIM + ks * 32 + quad * 8);
      a[1][ks] = *(const half8*)(zn + (size_t)ar1 * DIM + ks * 32 + quad * 8);
    }
  }

  // per-lane online softmax state; lane covers cols == cl (mod 16) of its rows
  float M[8], L[8];
  int AI[8];
#pragma unroll
  for (int s = 0; s < 8; s++) {
    M[s] = -3e38f;
    L[s] = 0.f;
    AI[s] = 0;
  }

  for (int t = 0; t < CPB / BN; t++) {  // 16 column tiles of 64
    __syncthreads();
    // stage B tile: 64 rows x 512B, xor-swizzle chunk index to break bank conflicts
#pragma unroll
    for (int i = 0; i < 8; i++) {
      int idx = tid + i * 256;
      int c = idx >> 5, ch = idx & 31;
      int g = colBase + t * BN + c;
      uint4 v = *(const uint4*)(zn + (size_t)g * DIM + ch * 8);
      lds[c * 32 + (ch ^ (c & 7))] = v;
    }
    __syncthreads();

    floatx4 acc[2][4];
#pragma unroll
    for (int rt = 0; rt < 2; rt++)
#pragma unroll
      for (int nt = 0; nt < 4; nt++) acc[rt][nt] = (floatx4){0.f, 0.f, 0.f, 0.f};

#pragma unroll
    for (int nt = 0; nt < 4; nt++) {
      int bc = nt * 16 + cl;
#pragma unroll
      for (int ks = 0; ks < 8; ks++) {
        int ch = ks * 4 + quad;
        half8 b = *(const half8*)&lds[bc * 32 + (ch ^ (bc & 7))];
        acc[0][nt] = __builtin_amdgcn_mfma_f32_16x16x32_f16(a[0][ks], b, acc[0][nt], 0, 0, 0);
        acc[1][nt] = __builtin_amdgcn_mfma_f32_16x16x32_f16(a[1][ks], b, acc[1][nt], 0, 0, 0);
      }
    }

    // per-lane online update (no cross-lane traffic in hot loop)
    int colT = colBase + t * BN;
#pragma unroll
    for (int rt = 0; rt < 2; rt++) {
      int growB = rowBase + w * 32 + rt * 16 + quad * 4;
#pragma unroll
      for (int r = 0; r < 4; r++) {
        int grow = growB + r;
        float v0 = acc[rt][0][r], v1 = acc[rt][1][r];
        float v2 = acc[rt][2][r], v3 = acc[rt][3][r];
        int c0 = colT + cl;
        if (c0 == grow) v0 = NEG_BIG;
        if (c0 + 16 == grow) v1 = NEG_BIG;
        if (c0 + 32 == grow) v2 = NEG_BIG;
        if (c0 + 48 == grow) v3 = NEG_BIG;
        float mv = v0;
        int mi = c0;
        if (v1 > mv) { mv = v1; mi = c0 + 16; }
        if (v2 > mv) { mv = v2; mi = c0 + 32; }
        if (v3 > mv) { mv = v3; mi = c0 + 48; }
        int slot = rt * 4 + r;
        float Mo = M[slot];
        float Mn = fmaxf(Mo, mv);
        if (mv > Mo) AI[slot] = mi;  // strict >: first occurrence wins (cols ascend)
        float se = exp2f((v0 - Mn) * kk) + exp2f((v1 - Mn) * kk) +
                   exp2f((v2 - Mn) * kk) + exp2f((v3 - Mn) * kk);
        L[slot] = L[slot] * exp2f((Mo - Mn) * kk) + se;
        M[slot] = Mn;
      }
    }
  }

  // combine the 16 per-lane partials within each quad (rows are per-quad)
#pragma unroll
  for (int s = 0; s < 8; s++) {
    float m = M[s], l = L[s];
    int ai = AI[s];
#pragma unroll
    for (int sh = 1; sh < 16; sh <<= 1) {
      float om = __shfl_xor(m, sh);
      float ol = __shfl_xor(l, sh);
      int oi = __shfl_xor(ai, sh);
      float mn = fmaxf(m, om);
      l = l * exp2f((m - mn) * kk) + ol * exp2f((om - mn) * kk);
      if (om > m || (om == m && oi < ai)) ai = oi;
      m = mn;
    }
    M[s] = m;
    L[s] = l;
    AI[s] = ai;
  }

  if (cl == 0) {
#pragma unroll
    for (int rt = 0; rt < 2; rt++)
#pragma unroll
      for (int r = 0; r < 4; r++) {
        int grow = rowBase + w * 32 + rt * 16 + quad * 4 + r;
        int s = rt * 4 + r;
        int p = grow * COLSPLIT + colq;
        pM[p] = M[s];
        pL[p] = L[s];
        pI[p] = AI[s];
      }
  }

  // ---- deadlock-free "last block reduces": never waits on co-residency ----
  __threadfence();
  __syncthreads();
  if (tid == 0) {
    unsigned prev = __hip_atomic_fetch_add(cnt, 1u, __ATOMIC_ACQ_REL,
                                           __HIP_MEMORY_SCOPE_AGENT);
    lastFlag = (prev == (unsigned)(NBLK - 1)) ? 1 : 0;
  }
  __syncthreads();
  if (!lastFlag) return;

  // final reduce (R0's k_reduce math, verbatim): 8192 rows over 256 threads
  float lossSum = 0.f, corrSum = 0.f;
  for (int rr = 0; rr < NTOT / 256; rr++) {
    int row = rr * 256 + tid;
    float m = -3e38f;
    int idx = 0;
#pragma unroll
    for (int q = 0; q < COLSPLIT; q++) {
      float mq = pM[row * COLSPLIT + q];
      if (mq > m) { m = mq; idx = pI[row * COLSPLIT + q]; }
    }
    float Lt = 0.f;
#pragma unroll
    for (int q = 0; q < COLSPLIT; q++)
      Lt += pL[row * COLSPLIT + q] * exp2f((pM[row * COLSPLIT + q] - m) * kk);
    int tgt = (row < NHALF) ? row + NHALF : row - NHALF;
    float logpt = (tsim[row] - m) * invT - logf(Lt);
    lossSum += -logpt;
    corrSum += (idx == tgt) ? 1.f : 0.f;
  }
  float* sl = (float*)lds;  // reuse LDS for the block reduction
  float* sc = sl + 256;
  sl[tid] = lossSum;
  sc[tid] = corrSum;
  __syncthreads();
  for (int s2 = 128; s2 > 0; s2 >>= 1) {
    if (tid < s2) { sl[tid] += sl[tid + s2]; sc[tid] += sc[tid + s2]; }
    __syncthreads();
  }
  if (tid == 0) {
    out[0] = sl[0] * (1.0f / (float)NTOT);
    out[1] = sc[0] * 0.5f;
  }
}

extern "C" void kernel_launch(void* const* d_in, const int* in_sizes, int n_in,
                              void* d_out, int out_size, void* d_ws, size_t ws_size,
                              hipStream_t stream) {
  const float* z1 = (const float*)d_in[0];
  const float* z2 = (const float*)d_in[1];
  const float* logT = (const float*)d_in[2];

  // workspace layout (~4.83 MB, R0-proven footprint)
  char* ws = (char*)d_ws;
  __half* zn = (__half*)ws;                                   // 4 MB unit rows
  float* tsim = (float*)(ws + (size_t)(4 << 20));             // 32 KB target sims
  float* pM = (float*)(ws + (size_t)(4 << 20) + (32 << 10));  // 256 KB
  float* pL = pM + NTOT * COLSPLIT;                           // 256 KB
  int* pI = (int*)(pL + NTOT * COLSPLIT);                     // 256 KB
  unsigned int* cnt = (unsigned int*)(pI + NTOT * COLSPLIT);  // 4 B

  k_norm_tsim<<<NHALF / 4, 256, 0, stream>>>(z1, z2, zn, tsim, cnt);
  k_main<<<NBLK, 256, 0, stream>>>(zn, logT, pM, pL, pI, tsim, cnt, (float*)d_out);
}